// Round 10
// baseline (286.094 us; speedup 1.0000x reference)
//
#include <hip/hip_runtime.h>

#define B_ 16384
#define D_ 2048
#define P_ 64
#define K_ 5

#define BK 64          // k-chunk in elements
#define NCH (D_ / BK)  // 32
#define LDR 72         // LDS row stride in halves (16B-aligned rows, 2-way reads)
#define SPLIT_SC 2048.0f
#define SPLIT_INV (1.0f / 2048.0f)

typedef _Float16 half8 __attribute__((ext_vector_type(8)));
typedef _Float16 half4 __attribute__((ext_vector_type(4)));
typedef float f32x4 __attribute__((ext_vector_type(4)));

static __device__ __forceinline__ void split4(const float4 v, half4& hi, half4& lo) {
  const float f[4] = {v.x, v.y, v.z, v.w};
#pragma unroll
  for (int i = 0; i < 4; ++i) {
    const _Float16 h = (_Float16)f[i];
    hi[i] = h;
    lo[i] = (_Float16)((f[i] - (float)h) * SPLIT_SC);
  }
}

// ---------------------------------------------------------------------------
// K0: pre-split parent_W fp32 -> (whi, wlo) f16 pair in workspace (256 KB x2).
// One-time; lets k1 load B-fragments straight from L2 with zero split VALU.
// ---------------------------------------------------------------------------
__global__ __launch_bounds__(256) void k0_split(const float* __restrict__ W,
                                                _Float16* __restrict__ whi,
                                                _Float16* __restrict__ wlo) {
  const int i = (blockIdx.x * 256 + threadIdx.x) * 4;  // 0..131068
  const float4 v = *(const float4*)&W[i];
  half4 h, lo;
  split4(v, h, lo);
  *(half4*)&whi[i] = h;
  *(half4*)&wlo[i] = lo;
}

// ---------------------------------------------------------------------------
// K1: parent GEMM via split-f16 MFMA, fused epilogue (bias+logits+argmax+
// expert lists). grid 1024 x 256 thr: block = 16 rows x 64 cols, full D.
// 4 blocks/CU x 4 waves = 16 waves/CU (round-7 killer was 1 block/CU).
// x: staged hi/lo to dbuf LDS (9 KB). W: per-lane 16B B-frags direct from
// L2 (pre-split). One barrier per chunk; acc = 2 x f32x4 -> ~60 VGPR.
// ---------------------------------------------------------------------------
__global__ __launch_bounds__(256) void k1_parent(
    const float* __restrict__ x, const _Float16* __restrict__ whi,
    const _Float16* __restrict__ wlo, const float* __restrict__ pb,
    float* __restrict__ pout, int* __restrict__ cnt, int* __restrict__ list) {
  __shared__ _Float16 xlh[2][16 * LDR], xll[2][16 * LDR];  // 9 KB total
  __shared__ float rmax[16][4];
  __shared__ int ridx[16][4];

  const int tid = threadIdx.x;
  const int b0 = blockIdx.x * 16;
  const int w = tid >> 6;  // wave: cols 16w..16w+15
  const int l = tid & 63;
  const int sr = tid >> 4;  // staging row 0..15
  const int sc = tid & 15;  // staging float-quad 0..15

  const float* xg = x + (size_t)(b0 + sr) * D_ + sc * 4;
  const float bias = pb[w * 16 + (l & 15)];

  const int aoff = (l & 15) * LDR + (l >> 4) * 8;  // A-frag halves offset
  const int soff = sr * LDR + sc * 4;              // staging halves offset
  const _Float16* bhp = whi + (size_t)(w * 16 + (l & 15)) * D_ + (l >> 4) * 8;
  const _Float16* blp = wlo + (size_t)(w * 16 + (l & 15)) * D_ + (l >> 4) * 8;

  f32x4 acc = {0.f, 0.f, 0.f, 0.f}, accc = {0.f, 0.f, 0.f, 0.f};

  {  // prologue: stage chunk 0 -> buf 0
    const float4 v = *(const float4*)xg;
    half4 h, lo;
    split4(v, h, lo);
    *(half4*)&xlh[0][soff] = h;
    *(half4*)&xll[0][soff] = lo;
  }
  __syncthreads();

  for (int ch = 0; ch < NCH; ++ch) {
    const int cur = ch & 1;
    const bool more = (ch + 1 < NCH);
    float4 xv;
    if (more) xv = *(const float4*)(xg + (ch + 1) * BK);  // prefetch next x

    // B-frags for both k32 steps: 4 independent 16B L2 loads in flight
    const half8 bh0 = *(const half8*)&bhp[ch * BK];
    const half8 bl0 = *(const half8*)&blp[ch * BK];
    const half8 bh1 = *(const half8*)&bhp[ch * BK + 32];
    const half8 bl1 = *(const half8*)&blp[ch * BK + 32];
    // A-frags from LDS (16B aligned, 2-way bank access)
    const half8 ah0 = *(const half8*)&xlh[cur][aoff];
    const half8 al0 = *(const half8*)&xll[cur][aoff];
    const half8 ah1 = *(const half8*)&xlh[cur][aoff + 32];
    const half8 al1 = *(const half8*)&xll[cur][aoff + 32];

    acc  = __builtin_amdgcn_mfma_f32_16x16x32_f16(ah0, bh0, acc, 0, 0, 0);
    accc = __builtin_amdgcn_mfma_f32_16x16x32_f16(ah0, bl0, accc, 0, 0, 0);
    accc = __builtin_amdgcn_mfma_f32_16x16x32_f16(al0, bh0, accc, 0, 0, 0);
    acc  = __builtin_amdgcn_mfma_f32_16x16x32_f16(ah1, bh1, acc, 0, 0, 0);
    accc = __builtin_amdgcn_mfma_f32_16x16x32_f16(ah1, bl1, accc, 0, 0, 0);
    accc = __builtin_amdgcn_mfma_f32_16x16x32_f16(al1, bh1, accc, 0, 0, 0);

    if (more) {  // stage next chunk into the other buffer
      half4 h, lo;
      split4(xv, h, lo);
      *(half4*)&xlh[cur ^ 1][soff] = h;
      *(half4*)&xll[cur ^ 1][soff] = lo;
    }
    __syncthreads();
  }

  // ---- fused epilogue ----
  const int colbase = w * 16 + (l & 15);
  float val[4];
#pragma unroll
  for (int j = 0; j < 4; ++j) {
    val[j] = acc[j] + accc[j] * SPLIT_INV + bias;
    const int row = ((l >> 4) << 2) + j;  // C/D: row=(lane>>4)*4+reg
    pout[(size_t)(b0 + row) * P_ + colbase] = val[j];
  }
  // argmax over this wave's 16 cols for each of the 4 rows this lane holds
#pragma unroll
  for (int j = 0; j < 4; ++j) {
    float bv = val[j];
    int bi = colbase;
#pragma unroll
    for (int s = 8; s > 0; s >>= 1) {
      const float ov = __shfl_xor(bv, s, 64);
      const int oi = __shfl_xor(bi, s, 64);
      if (ov > bv || (ov == bv && oi < bi)) { bv = ov; bi = oi; }
    }
    if ((l & 15) == 0) {
      rmax[((l >> 4) << 2) + j][w] = bv;
      ridx[((l >> 4) << 2) + j][w] = bi;
    }
  }
  __syncthreads();
  if (tid < 16) {
    float bv = rmax[tid][0];
    int bi = ridx[tid][0];
#pragma unroll
    for (int ww = 1; ww < 4; ++ww) {
      const float ov = rmax[tid][ww];
      const int oi = ridx[tid][ww];
      if (ov > bv || (ov == bv && oi < bi)) { bv = ov; bi = oi; }
    }
    const int slot = atomicAdd(&cnt[bi * 16], 1);  // 64B-padded counters
    if (slot < 1024) list[bi * 1024 + slot] = b0 + tid;
  }
}

// ---------------------------------------------------------------------------
// K2: child logits from dense row lists (fp32 VALU). grid = 64 experts x 16
// chunks (4 blocks/CU for latency hiding). 4 rows batched per W pass;
// pair-packed butterfly reduce.
// ---------------------------------------------------------------------------
__global__ __launch_bounds__(256) void k2_child(const float* __restrict__ x,
                                                const float* __restrict__ cW,
                                                const float* __restrict__ cb,
                                                const int* __restrict__ cnt,
                                                const int* __restrict__ list,
                                                float* __restrict__ cout) {
  __shared__ float wlds[K_ * D_];  // 40 KB
  const int e = blockIdx.x >> 4;
  const int chk = blockIdx.x & 15;
  const int tid = threadIdx.x;

  const float4* wg4 = (const float4*)(cW + (size_t)e * (K_ * D_));
  float4* wl4 = (float4*)wlds;
#pragma unroll
  for (int tI = 0; tI < 10; ++tI) wl4[tid + 256 * tI] = wg4[tid + 256 * tI];
  __syncthreads();

  const int n = min(cnt[e * 16], 1024);
  const int per = (n + 15) >> 4;
  const int lo = chk * per;
  const int hi = min(lo + per, n);
  const int m = hi - lo;
  if (m <= 0) return;

  const int wave = tid >> 6, lane = tid & 63;
  const int wper = (m + 3) >> 2;
  const int wlo = lo + wave * wper;
  const int whi_ = min(wlo + wper, hi);

  const float4* x4 = (const float4*)x;
  const int* mylist = list + e * 1024;

  for (int i0 = wlo; i0 < whi_; i0 += 4) {
    const int vb = min(4, whi_ - i0);
    const int ra = mylist[i0];
    const int rb = mylist[i0 + min(1, vb - 1)];
    const int rc = mylist[i0 + min(2, vb - 1)];
    const int rd = mylist[i0 + min(3, vb - 1)];

    float a[20];
#pragma unroll
    for (int q = 0; q < 20; ++q) a[q] = 0.f;

#pragma unroll
    for (int tt = 0; tt < 8; ++tt) {
      const float4 xv0 = x4[(size_t)ra * 512 + lane + 64 * tt];
      const float4 xv1 = x4[(size_t)rb * 512 + lane + 64 * tt];
      const float4 xv2 = x4[(size_t)rc * 512 + lane + 64 * tt];
      const float4 xv3 = x4[(size_t)rd * 512 + lane + 64 * tt];
#pragma unroll
      for (int k = 0; k < 5; ++k) {
        const float4 wv = wl4[k * 512 + lane + 64 * tt];
        a[0 * 5 + k] += xv0.x * wv.x + xv0.y * wv.y + xv0.z * wv.z + xv0.w * wv.w;
        a[1 * 5 + k] += xv1.x * wv.x + xv1.y * wv.y + xv1.z * wv.z + xv1.w * wv.w;
        a[2 * 5 + k] += xv2.x * wv.x + xv2.y * wv.y + xv2.z * wv.z + xv2.w * wv.w;
        a[3 * 5 + k] += xv3.x * wv.x + xv3.y * wv.y + xv3.z * wv.z + xv3.w * wv.w;
      }
    }
#pragma unroll
    for (int p = 0; p < 10; ++p) {
      float va = a[2 * p], vb2 = a[2 * p + 1];
      va += __shfl_xor(va, 32, 64);
      vb2 += __shfl_xor(vb2, 32, 64);
      float z = (lane < 32) ? va : vb2;
      z += __shfl_xor(z, 16, 64);
      z += __shfl_xor(z, 8, 64);
      z += __shfl_xor(z, 4, 64);
      z += __shfl_xor(z, 2, 64);
      z += __shfl_xor(z, 1, 64);
      a[2 * p] = z;
    }
    if (lane == 0 || lane == 32) {
      const int off = (lane == 32) ? 1 : 0;
#pragma unroll
      for (int p = 0; p < 10; ++p) {
        const int f = 2 * p + off;
        const int rr = f / 5, kk = f % 5;
        if (rr < vb) {
          const int rX = (rr == 0) ? ra : (rr == 1) ? rb : (rr == 2) ? rc : rd;
          cout[(size_t)rX * K_ + kk] = a[2 * p] + cb[e * K_ + kk];
        }
      }
    }
  }
}

extern "C" void kernel_launch(void* const* d_in, const int* in_sizes, int n_in,
                              void* d_out, int out_size, void* d_ws, size_t ws_size,
                              hipStream_t stream) {
  const float* x  = (const float*)d_in[0];
  const float* pW = (const float*)d_in[1];
  const float* pb = (const float*)d_in[2];
  const float* cW = (const float*)d_in[3];
  const float* cb = (const float*)d_in[4];
  float* pout = (float*)d_out;                    // [B, 64]
  float* cout = (float*)d_out + (size_t)B_ * P_;  // [B, 5]

  char* ws = (char*)d_ws;
  _Float16* whi = (_Float16*)ws;              // 256 KB
  _Float16* wlo = (_Float16*)(ws + 262144);   // 256 KB
  int* cnt  = (int*)(ws + 524288);            // 64 counters, 64 B apart
  int* list = (int*)(ws + 528384);            // 64 x 1024 ints (256 KB)

  hipMemsetAsync(cnt, 0, 4096, stream);
  k0_split<<<128, 256, 0, stream>>>(pW, whi, wlo);
  k1_parent<<<B_ / 16, 256, 0, stream>>>(x, whi, wlo, pb, pout, cnt, list);
  k2_child<<<P_ * 16, 256, 0, stream>>>(x, cW, cb, cnt, list, cout);
}